// Round 3
// baseline (175.757 us; speedup 1.0000x reference)
//
#include <hip/hip_runtime.h>
#include <cstdint>
#include <cstddef>

// Problem constants
constexpr int N = 4096;
constexpr int B = 32;
constexpr int BN = B * N;             // 131072
constexpr size_t NN = (size_t)N * N;  // 16777216
constexpr int KCHUNKS = 4;            // K-split (partial buffers)
constexpr int CHUNK = N / KCHUNKS;    // 1024 k per block
constexpr int KW = CHUNK / 4;         // 256 k per wave
constexpr int NIT = KW / 32;          // 8 MFMA iterations per wave

constexpr float ALPHA = 0.025f;
constexpr float BETA = 0.00025f;
constexpr float T_NOW = 10.0f;
constexpr float INV_EXP_TAU = 0.02f;          // 1/50
constexpr float INV_TAU_V = 0.98019867f;      // exp(-1/50)
constexpr float INV_TAU_I = 0.36787944f;      // exp(-1)

typedef __attribute__((ext_vector_type(8))) short short8;
typedef __attribute__((ext_vector_type(4))) float f32x4;

__device__ inline unsigned short f2bf(float f) {
  uint32_t u = __float_as_uint(f);
  u += 0x7FFFu + ((u >> 16) & 1u);   // RNE
  return (unsigned short)(u >> 16);
}

// W-update recomputed on the fly:
//   u = clip(w + BETA - fac_row * exp(|mst_row - mst_col|/50), 0, 1); keep w where w<=0
__device__ inline float wupd(float w, float mrow, float frow, float mcol) {
  float d = fabsf(mrow - mcol);
  float u = w + BETA - frow * __expf(d * INV_EXP_TAU);
  u = fminf(fmaxf(u, 0.0f), 1.0f);
  return (w > 0.0f) ? u : w;
}

// ---------------------------------------------------------------------------
// Pass A: per-neuron spike masks + max_st + rowfac; writes S (f32) and S_bf
// (bf16 copy, the MFMA A-matrix).
// ---------------------------------------------------------------------------
__global__ __launch_bounds__(256) void pass_a(
    const float* __restrict__ mem_pot, const float* __restrict__ mem_pot_p,
    const float* __restrict__ st, float* __restrict__ S_out,
    unsigned short* __restrict__ S_bf,
    uint32_t* __restrict__ maskS, uint32_t* __restrict__ maskSP,
    float* __restrict__ max_st, float* __restrict__ rowfac) {
  int j = blockIdx.x * blockDim.x + threadIdx.x;
  if (j >= N) return;
  float stj = st[j];
  uint32_t ms = 0u, msp = 0u;
  float maxv = -3.0e38f;
  #pragma unroll
  for (int b = 0; b < B; ++b) {
    float p = mem_pot[b * N + j];
    float pp = mem_pot_p[b * N + j];
    bool s = (p - 1.0f) > 0.0f;
    bool sp = ((pp - 1.0f) - ALPHA) > 0.0f;
    S_out[b * N + j] = s ? 1.0f : 0.0f;
    S_bf[b * N + j] = s ? 0x3F80u : 0u;   // bf16 1.0 / 0.0
    ms |= (uint32_t)s << b;
    msp |= (uint32_t)sp << b;
    maxv = fmaxf(maxv, s ? T_NOW : stj);
  }
  maskS[j] = ms;
  maskSP[j] = msp;
  max_st[j] = maxv;
  rowfac[j] = msp ? ALPHA : 0.0f;
}

// ---------------------------------------------------------------------------
// Fused pass: W-update recomputed on the fly inside BOTH skinny GEMMs.
//   gemm 0 (z==0): SW[b,j]  += sum_k S[b,k]*Wnew[k,j]
//   gemm 1 (z==1): SWT[b,i] += sum_j S[b,j]*Wnew[i,j]; writes W_out (exact 1x)
// Block = (16-wide n-tile, k-chunk of 1024); 4 waves SHARE the n-tile and
// split the chunk 4-way (256 k each, software-pipelined prefetch), then
// LDS-reduce the 4 partial accumulators -> ONE partial-buffer store.
// MFMA layouts (verified): A[m=lane&15][k=quad*8+i], B[k=quad*8+i][n=lane&15],
// C/D: col=lane&15, row=quad*4+reg.
// ---------------------------------------------------------------------------
__global__ __launch_bounds__(256, 6) void pass_fused(
    const float* __restrict__ W, const unsigned short* __restrict__ S_bf,
    const float* __restrict__ max_st, const float* __restrict__ rowfac,
    float* __restrict__ Wout, float* __restrict__ partSW,
    float* __restrict__ partSWT) {
  __shared__ float mstK[CHUNK];
  __shared__ float facK[CHUNK];
  __shared__ float red[4][32][17];   // +1 pad breaks bank aliasing

  int tid = threadIdx.x;
  int wv = tid >> 6;
  int lane = tid & 63;
  int j0 = blockIdx.x * 16;          // n-tile (shared by all 4 waves)
  int kbase = blockIdx.y * CHUNK;
  int gemm = blockIdx.z;
  int quad = lane >> 4;
  int nl = lane & 15;

  // stage the chunk's row/col vectors in LDS
  for (int t = tid; t < CHUNK; t += 256) {
    mstK[t] = max_st[kbase + t];
    facK[t] = rowfac[kbase + t];
  }
  __syncthreads();

  f32x4 acc0 = {0.f, 0.f, 0.f, 0.f};
  f32x4 acc1 = {0.f, 0.f, 0.f, 0.f};
  const unsigned short* A0p = S_bf + (size_t)nl * N;          // batches 0-15
  const unsigned short* A1p = S_bf + (size_t)(nl + 16) * N;   // batches 16-31
  int kw = kbase + wv * KW;          // this wave's global k start

  if (gemm == 0) {
    // element W[k][j0+nl]: row k (mstK/facK), col j0+nl (mj)
    float mj = max_st[j0 + nl];
    const float* wp0 = W + (size_t)(kw + quad * 8) * N + j0 + nl;
    float w[8];
    #pragma unroll
    for (int i = 0; i < 8; ++i) w[i] = wp0[(size_t)i * N];
    #pragma unroll
    for (int it = 0; it < NIT; ++it) {
      int kloc = wv * KW + it * 32 + quad * 8;   // index into mstK/facK
      int kg = kw + it * 32 + quad * 8;          // global k
      short8 a0 = *(const short8*)(A0p + kg);
      short8 a1 = *(const short8*)(A1p + kg);
      float wn[8];
      if (it + 1 < NIT) {                        // prefetch next iteration
        const float* wpn = wp0 + (size_t)(it + 1) * 32 * N;
        #pragma unroll
        for (int i = 0; i < 8; ++i) wn[i] = wpn[(size_t)i * N];
      }
      float4 m4a = *(const float4*)(mstK + kloc);
      float4 m4b = *(const float4*)(mstK + kloc + 4);
      float4 f4a = *(const float4*)(facK + kloc);
      float4 f4b = *(const float4*)(facK + kloc + 4);
      short8 bf;
      bf[0] = (short)f2bf(wupd(w[0], m4a.x, f4a.x, mj));
      bf[1] = (short)f2bf(wupd(w[1], m4a.y, f4a.y, mj));
      bf[2] = (short)f2bf(wupd(w[2], m4a.z, f4a.z, mj));
      bf[3] = (short)f2bf(wupd(w[3], m4a.w, f4a.w, mj));
      bf[4] = (short)f2bf(wupd(w[4], m4b.x, f4b.x, mj));
      bf[5] = (short)f2bf(wupd(w[5], m4b.y, f4b.y, mj));
      bf[6] = (short)f2bf(wupd(w[6], m4b.z, f4b.z, mj));
      bf[7] = (short)f2bf(wupd(w[7], m4b.w, f4b.w, mj));
      acc0 = __builtin_amdgcn_mfma_f32_16x16x32_bf16(a0, bf, acc0, 0, 0, 0);
      acc1 = __builtin_amdgcn_mfma_f32_16x16x32_bf16(a1, bf, acc1, 0, 0, 0);
      if (it + 1 < NIT) {
        #pragma unroll
        for (int i = 0; i < 8; ++i) w[i] = wn[i];
      }
    }
  } else {
    // element W[j0+nl][k]: row j0+nl (mi, fi), col k (mstK). Writes W_out.
    float mi = max_st[j0 + nl];
    float fi = rowfac[j0 + nl];
    const float* __restrict__ wrp = W + (size_t)(j0 + nl) * N + kw + quad * 8;
    float* __restrict__ worp = Wout + (size_t)(j0 + nl) * N + kw + quad * 8;
    float4 f0 = *(const float4*)(wrp);
    float4 f1 = *(const float4*)(wrp + 4);
    #pragma unroll
    for (int it = 0; it < NIT; ++it) {
      int kloc = wv * KW + it * 32 + quad * 8;
      int kg = kw + it * 32 + quad * 8;
      short8 a0 = *(const short8*)(A0p + kg);
      short8 a1 = *(const short8*)(A1p + kg);
      float4 g0, g1;
      if (it + 1 < NIT) {                        // prefetch next iteration
        g0 = *(const float4*)(wrp + (it + 1) * 32);
        g1 = *(const float4*)(wrp + (it + 1) * 32 + 4);
      }
      float4 m4a = *(const float4*)(mstK + kloc);
      float4 m4b = *(const float4*)(mstK + kloc + 4);
      float4 u0, u1;
      u0.x = wupd(f0.x, mi, fi, m4a.x);
      u0.y = wupd(f0.y, mi, fi, m4a.y);
      u0.z = wupd(f0.z, mi, fi, m4a.z);
      u0.w = wupd(f0.w, mi, fi, m4a.w);
      u1.x = wupd(f1.x, mi, fi, m4b.x);
      u1.y = wupd(f1.y, mi, fi, m4b.y);
      u1.z = wupd(f1.z, mi, fi, m4b.z);
      u1.w = wupd(f1.w, mi, fi, m4b.w);
      *(float4*)(worp + it * 32) = u0;
      *(float4*)(worp + it * 32 + 4) = u1;
      short8 bf;
      bf[0] = (short)f2bf(u0.x); bf[1] = (short)f2bf(u0.y);
      bf[2] = (short)f2bf(u0.z); bf[3] = (short)f2bf(u0.w);
      bf[4] = (short)f2bf(u1.x); bf[5] = (short)f2bf(u1.y);
      bf[6] = (short)f2bf(u1.z); bf[7] = (short)f2bf(u1.w);
      acc0 = __builtin_amdgcn_mfma_f32_16x16x32_bf16(a0, bf, acc0, 0, 0, 0);
      acc1 = __builtin_amdgcn_mfma_f32_16x16x32_bf16(a1, bf, acc1, 0, 0, 0);
      if (it + 1 < NIT) { f0 = g0; f1 = g1; }
    }
  }

  // 4-wave LDS reduction; C/D: col = lane&15 (n), row = quad*4+reg (batch).
  #pragma unroll
  for (int r = 0; r < 4; ++r) {
    red[wv][quad * 4 + r][nl] = acc0[r];
    red[wv][16 + quad * 4 + r][nl] = acc1[r];
  }
  __syncthreads();
  // 512 outputs (32 batches x 16 cols) with 256 threads: 2 rows per thread.
  {
    int row = tid >> 4;        // batch 0..15
    int col = tid & 15;        // n within tile
    float* part = (gemm == 0) ? partSW : partSWT;
    size_t base = (size_t)blockIdx.y * BN + j0 + col;
    float s0 = red[0][row][col] + red[1][row][col] +
               red[2][row][col] + red[3][row][col];
    float s1 = red[0][row + 16][col] + red[1][row + 16][col] +
               red[2][row + 16][col] + red[3][row + 16][col];
    part[base + (size_t)row * N] = s0;
    part[base + (size_t)(row + 16) * N] = s1;
  }
}

// ---------------------------------------------------------------------------
// Pass D: reduce K-partials, integrate + leak + reset + refractory.
// ---------------------------------------------------------------------------
__global__ __launch_bounds__(256) void pass_d(
    const float* __restrict__ inp, const float* __restrict__ mem_pot,
    const float* __restrict__ mem_cur, const float* __restrict__ mem_pot_p,
    const float* __restrict__ mem_cur_p, const int* __restrict__ refrac_in,
    const uint32_t* __restrict__ maskS, const uint32_t* __restrict__ maskSP,
    const float* __restrict__ partSW, const float* __restrict__ partSWT,
    float* __restrict__ pot_out, float* __restrict__ cur_out,
    float* __restrict__ potp_out, float* __restrict__ curp_out,
    float* __restrict__ refrac_out) {
  int e = blockIdx.x * 256 + threadIdx.x;
  int b = e >> 12;
  int j = e & (N - 1);

  float SW = 0.0f, SWT = 0.0f;
  #pragma unroll
  for (int c = 0; c < KCHUNKS; ++c) {
    SW += partSW[(size_t)c * BN + e];
    SWT += partSWT[(size_t)c * BN + e];
  }

  int r = refrac_in[e];
  int rd = (r > 0) ? (r - 1) : r;
  bool active = (rd == 0);
  bool s = (maskS[j] >> b) & 1u;
  bool sp = (maskSP[j] >> b) & 1u;
  float cur = mem_cur[e], pot = mem_pot[e];
  float curp = mem_cur_p[e], potp = mem_pot_p[e];

  float cur_n = active ? (inp[e] + SW + cur) : cur;
  float curp_n = active ? (SWT + curp) : curp;
  float pot_n = active ? (cur_n + pot) : pot;
  float potp_n = active ? (curp_n + potp) : potp;

  pot_n *= INV_TAU_V;
  cur_n *= INV_TAU_I;
  potp_n *= INV_TAU_V;
  curp_n *= INV_TAU_I;

  if (s) pot_n = 0.0f;
  if (sp) potp_n = 0.0f;
  int rn = s ? 2 : rd;

  pot_out[e] = pot_n;
  cur_out[e] = cur_n;
  potp_out[e] = potp_n;
  curp_out[e] = curp_n;
  refrac_out[e] = (float)rn;
}

// ---------------------------------------------------------------------------
extern "C" void kernel_launch(void* const* d_in, const int* in_sizes, int n_in,
                              void* d_out, int out_size, void* d_ws, size_t ws_size,
                              hipStream_t stream) {
  const float* inp = (const float*)d_in[0];
  const float* W = (const float*)d_in[1];
  const float* mem_pot = (const float*)d_in[2];
  const float* mem_cur = (const float*)d_in[3];
  const float* mem_pot_p = (const float*)d_in[4];
  const float* mem_cur_p = (const float*)d_in[5];
  const float* st = (const float*)d_in[6];
  const int* refrac = (const int*)d_in[7];

  float* out = (float*)d_out;
  float* S_out = out;
  float* pot_out = out + BN;
  float* W_out = out + 2 * (size_t)BN;
  float* cur_out = W_out + NN;
  float* potp_out = cur_out + BN;
  float* curp_out = potp_out + BN;
  float* refrac_out = curp_out + BN;

  // Workspace layout (16B-aligned), ~4.5 MB total (proven budget)
  uint32_t* maskS = (uint32_t*)d_ws;                      // 16 KB
  uint32_t* maskSP = maskS + N;                           // 16 KB
  float* max_st = (float*)(maskSP + N);                   // 16 KB
  float* rowfac = max_st + N;                             // 16 KB
  unsigned short* S_bf = (unsigned short*)(rowfac + N);   // 256 KB
  float* partSW = (float*)(S_bf + BN);                    // KCHUNKS*BN*4 = 2 MB
  float* partSWT = partSW + (size_t)KCHUNKS * BN;         // 2 MB

  pass_a<<<N / 256, 256, 0, stream>>>(mem_pot, mem_pot_p, st, S_out, S_bf,
                                      maskS, maskSP, max_st, rowfac);
  pass_fused<<<dim3(N / 16, KCHUNKS, 2), 256, 0, stream>>>(
      W, S_bf, max_st, rowfac, W_out, partSW, partSWT);
  pass_d<<<BN / 256, 256, 0, stream>>>(inp, mem_pot, mem_cur, mem_pot_p,
                                       mem_cur_p, refrac, maskS, maskSP,
                                       partSW, partSWT, pot_out, cur_out,
                                       potp_out, curp_out, refrac_out);
}

// Round 4
// 155.995 us; speedup vs baseline: 1.1267x; 1.1267x over previous
//
#include <hip/hip_runtime.h>
#include <cstdint>
#include <cstddef>

// Problem constants
constexpr int N = 4096;
constexpr int B = 32;
constexpr int BN = B * N;             // 131072
constexpr size_t NN = (size_t)N * N;  // 16777216

// Fused-pass tiling: each block owns a TI x TJ tile of W, read ONCE coalesced.
constexpr int TI = 256;               // i-rows per block
constexpr int TJ = 128;               // j-cols per block
constexpr int NIT = N / TI;           // 16 it partials (partSW copies)
constexpr int NJT = N / TJ;           // 32 jt partials (partSWT copies)
constexpr int ISUB = 64;              // rows per sub-tile
constexpr int LDT = TJ + 8;           // 136 bf16 elems: row stride (16B-aligned, pads banks)

constexpr float ALPHA = 0.025f;
constexpr float BETA = 0.00025f;
constexpr float T_NOW = 10.0f;
constexpr float INV_EXP_TAU = 0.02f;          // 1/50
constexpr float INV_TAU_V = 0.98019867f;      // exp(-1/50)
constexpr float INV_TAU_I = 0.36787944f;      // exp(-1)

typedef __attribute__((ext_vector_type(8))) short short8;
typedef __attribute__((ext_vector_type(4))) float f32x4;

__device__ inline unsigned short f2bf(float f) {
  uint32_t u = __float_as_uint(f);
  u += 0x7FFFu + ((u >> 16) & 1u);   // RNE
  return (unsigned short)(u >> 16);
}

// W-update recomputed on the fly:
//   u = clip(w + BETA - fac_row * exp(|mst_row - mst_col|/50), 0, 1); keep w where w<=0
__device__ inline float wupd(float w, float mrow, float frow, float mcol) {
  float d = fabsf(mrow - mcol);
  float u = w + BETA - frow * __expf(d * INV_EXP_TAU);
  u = fminf(fmaxf(u, 0.0f), 1.0f);
  return (w > 0.0f) ? u : w;
}

// ---------------------------------------------------------------------------
// Pass A: per-neuron spike masks + max_st + rowfac; writes S (f32) and S_bf
// (bf16 copy, the MFMA A-matrix).
// ---------------------------------------------------------------------------
__global__ __launch_bounds__(256) void pass_a(
    const float* __restrict__ mem_pot, const float* __restrict__ mem_pot_p,
    const float* __restrict__ st, float* __restrict__ S_out,
    unsigned short* __restrict__ S_bf,
    uint32_t* __restrict__ maskS, uint32_t* __restrict__ maskSP,
    float* __restrict__ max_st, float* __restrict__ rowfac) {
  int j = blockIdx.x * blockDim.x + threadIdx.x;
  if (j >= N) return;
  float stj = st[j];
  uint32_t ms = 0u, msp = 0u;
  float maxv = -3.0e38f;
  #pragma unroll
  for (int b = 0; b < B; ++b) {
    float p = mem_pot[b * N + j];
    float pp = mem_pot_p[b * N + j];
    bool s = (p - 1.0f) > 0.0f;
    bool sp = ((pp - 1.0f) - ALPHA) > 0.0f;
    S_out[b * N + j] = s ? 1.0f : 0.0f;
    S_bf[b * N + j] = s ? 0x3F80u : 0u;   // bf16 1.0 / 0.0
    ms |= (uint32_t)s << b;
    msp |= (uint32_t)sp << b;
    maxv = fmaxf(maxv, s ? T_NOW : stj);
  }
  maskS[j] = ms;
  maskSP[j] = msp;
  max_st[j] = maxv;
  rowfac[j] = msp ? ALPHA : 0.0f;
}

// ---------------------------------------------------------------------------
// Fused single-W-read pass. Block (jt, it) owns W[i0:i0+256][j0:j0+128]:
//   - loads the tile ONCE, coalesced float4, in 4 sub-tiles of 64x128
//   - computes Wnew (wupd), writes W_out coalesced (exact 1x coverage)
//   - parks bf16 Wnew in LDS; serves BOTH GEMMs from LDS:
//       gemm0 SW[b,j]  = sum_i S[b,i]*Wnew[i,j]  (waves 0-3, col-frags, u16)
//       gemm1 SWT[b,i] = sum_j S[b,j]*Wnew[i,j]  (waves 4-7, row-frags, b128)
//   - partial sums -> partSW[it][b][j] and partSWT[jt][b][i] (no atomics)
// MFMA layouts (verified in prior rounds): A[m=lane&15][k=quad*8+e],
// B[k=quad*8+e][n=lane&15], C/D: col=lane&15, row=quad*4+reg.
// ---------------------------------------------------------------------------
__global__ __launch_bounds__(512, 4) void pass_fused(
    const float* __restrict__ W, const unsigned short* __restrict__ S_bf,
    const float* __restrict__ max_st, const float* __restrict__ rowfac,
    float* __restrict__ Wout, float* __restrict__ partSW,
    float* __restrict__ partSWT) {
  __shared__ __align__(16) unsigned short tile[ISUB * LDT];  // 17408 B
  __shared__ float mstI[TI];
  __shared__ float facI[TI];
  __shared__ float mstJ[TJ];

  int tid = threadIdx.x;
  int wv = tid >> 6;
  int lane = tid & 63;
  int quad = lane >> 4;
  int nl = lane & 15;
  int jt = blockIdx.x;               // 0..31
  int it = blockIdx.y;               // 0..15
  int i0 = it * TI;
  int j0 = jt * TJ;

  uint32_t* tileU32 = (uint32_t*)tile;

  // prologue: stage per-row/col update vectors
  if (tid < TI) {
    mstI[tid] = max_st[i0 + tid];
    facI[tid] = rowfac[i0 + tid];
  } else if (tid < TI + TJ) {
    mstJ[tid - TI] = max_st[j0 + (tid - TI)];
  }

  // issue loads for sub-tile 0 (64 rows x 32 float4)
  float4 pf0, pf1, pf2, pf3;
  int row = tid >> 5;                // 0..15 within p-stripe
  int c4 = tid & 31;                 // float4 column
  {
    const float* base = W + (size_t)(i0 + row) * N + j0 + c4 * 4;
    pf0 = *(const float4*)(base);
    pf1 = *(const float4*)(base + (size_t)16 * N);
    pf2 = *(const float4*)(base + (size_t)32 * N);
    pf3 = *(const float4*)(base + (size_t)48 * N);
  }
  __syncthreads();   // mstI/facI/mstJ ready

  // gemm0 accumulators (waves 0-3): 2 j-subtiles x 2 batch-halves
  f32x4 accA0 = {0.f, 0.f, 0.f, 0.f}, accA1 = {0.f, 0.f, 0.f, 0.f};
  f32x4 accB0 = {0.f, 0.f, 0.f, 0.f}, accB1 = {0.f, 0.f, 0.f, 0.f};

  for (int isub = 0; isub < TI / ISUB; ++isub) {
    // ---- stage: wupd + W_out store + bf16 -> LDS ----
    float4 mj = *(const float4*)(mstJ + c4 * 4);
    #pragma unroll
    for (int p = 0; p < 4; ++p) {
      float4 w4 = (p == 0) ? pf0 : (p == 1) ? pf1 : (p == 2) ? pf2 : pf3;
      int r = p * 16 + row;                       // row within sub-tile
      int ig = i0 + isub * ISUB + r;
      float mi = mstI[isub * ISUB + r];
      float fi = facI[isub * ISUB + r];
      float4 u;
      u.x = wupd(w4.x, mi, fi, mj.x);
      u.y = wupd(w4.y, mi, fi, mj.y);
      u.z = wupd(w4.z, mi, fi, mj.z);
      u.w = wupd(w4.w, mi, fi, mj.w);
      *(float4*)(Wout + (size_t)ig * N + j0 + c4 * 4) = u;
      uint32_t d0 = (uint32_t)f2bf(u.x) | ((uint32_t)f2bf(u.y) << 16);
      uint32_t d1 = (uint32_t)f2bf(u.z) | ((uint32_t)f2bf(u.w) << 16);
      uint2 dd; dd.x = d0; dd.y = d1;
      *(uint2*)&tileU32[r * (LDT / 2) + c4 * 2] = dd;
    }
    // issue next sub-tile's loads (overlap with MFMA phase)
    if (isub + 1 < TI / ISUB) {
      const float* base =
          W + (size_t)(i0 + (isub + 1) * ISUB + row) * N + j0 + c4 * 4;
      pf0 = *(const float4*)(base);
      pf1 = *(const float4*)(base + (size_t)16 * N);
      pf2 = *(const float4*)(base + (size_t)32 * N);
      pf3 = *(const float4*)(base + (size_t)48 * N);
    }
    __syncthreads();   // tile writes visible

    // ---- MFMA phase ----
    if (wv < 4) {
      // gemm0: n-tiles js = wv*2, wv*2+1; K = this sub-tile's 64 rows
      int js0 = wv * 2, js1 = wv * 2 + 1;
      #pragma unroll
      for (int kstep = 0; kstep < 2; ++kstep) {
        int kl = kstep * 32 + quad * 8;
        int kglob = i0 + isub * ISUB + kl;
        short8 a0 = *(const short8*)(S_bf + (size_t)nl * N + kglob);
        short8 a1 = *(const short8*)(S_bf + (size_t)(nl + 16) * N + kglob);
        short8 b0, b1;
        #pragma unroll
        for (int e = 0; e < 8; ++e) {
          b0[e] = (short)tile[(kl + e) * LDT + js0 * 16 + nl];
          b1[e] = (short)tile[(kl + e) * LDT + js1 * 16 + nl];
        }
        accA0 = __builtin_amdgcn_mfma_f32_16x16x32_bf16(a0, b0, accA0, 0, 0, 0);
        accA1 = __builtin_amdgcn_mfma_f32_16x16x32_bf16(a1, b0, accA1, 0, 0, 0);
        accB0 = __builtin_amdgcn_mfma_f32_16x16x32_bf16(a0, b1, accB0, 0, 0, 0);
        accB1 = __builtin_amdgcn_mfma_f32_16x16x32_bf16(a1, b1, accB1, 0, 0, 0);
      }
    } else {
      // gemm1: n = 16 i's (wave's subtile), K = full TJ=128; complete per isub
      int ws = wv - 4;
      int il = ws * 16 + nl;                      // row within sub-tile
      f32x4 g0 = {0.f, 0.f, 0.f, 0.f}, g1 = {0.f, 0.f, 0.f, 0.f};
      #pragma unroll
      for (int kstep = 0; kstep < 4; ++kstep) {
        int kl = kstep * 32 + quad * 8;
        int kglobJ = j0 + kl;
        short8 a0 = *(const short8*)(S_bf + (size_t)nl * N + kglobJ);
        short8 a1 = *(const short8*)(S_bf + (size_t)(nl + 16) * N + kglobJ);
        short8 bfr = *(const short8*)&tile[il * LDT + kl];
        g0 = __builtin_amdgcn_mfma_f32_16x16x32_bf16(a0, bfr, g0, 0, 0, 0);
        g1 = __builtin_amdgcn_mfma_f32_16x16x32_bf16(a1, bfr, g1, 0, 0, 0);
      }
      int iglob = i0 + isub * ISUB + il;
      size_t basew = (size_t)jt * BN + iglob;
      #pragma unroll
      for (int r = 0; r < 4; ++r) {
        partSWT[basew + (size_t)(quad * 4 + r) * N] = g0[r];
        partSWT[basew + (size_t)(16 + quad * 4 + r) * N] = g1[r];
      }
    }
    if (isub + 1 < TI / ISUB) __syncthreads();  // tile reads done before overwrite
  }

  // epilogue: gemm0 partial stores (K=256 fully accumulated)
  if (wv < 4) {
    int jg0 = j0 + (wv * 2) * 16 + nl;
    int jg1 = j0 + (wv * 2 + 1) * 16 + nl;
    size_t baseit = (size_t)it * BN;
    #pragma unroll
    for (int r = 0; r < 4; ++r) {
      partSW[baseit + (size_t)(quad * 4 + r) * N + jg0] = accA0[r];
      partSW[baseit + (size_t)(16 + quad * 4 + r) * N + jg0] = accA1[r];
      partSW[baseit + (size_t)(quad * 4 + r) * N + jg1] = accB0[r];
      partSW[baseit + (size_t)(16 + quad * 4 + r) * N + jg1] = accB1[r];
    }
  }
}

// ---------------------------------------------------------------------------
// Pass D: reduce partials, integrate + leak + reset + refractory.
// ---------------------------------------------------------------------------
__global__ __launch_bounds__(256) void pass_d(
    const float* __restrict__ inp, const float* __restrict__ mem_pot,
    const float* __restrict__ mem_cur, const float* __restrict__ mem_pot_p,
    const float* __restrict__ mem_cur_p, const int* __restrict__ refrac_in,
    const uint32_t* __restrict__ maskS, const uint32_t* __restrict__ maskSP,
    const float* __restrict__ partSW, const float* __restrict__ partSWT,
    float* __restrict__ pot_out, float* __restrict__ cur_out,
    float* __restrict__ potp_out, float* __restrict__ curp_out,
    float* __restrict__ refrac_out) {
  int e = blockIdx.x * 256 + threadIdx.x;
  int b = e >> 12;
  int j = e & (N - 1);

  float SW = 0.0f, SWT = 0.0f;
  #pragma unroll
  for (int c = 0; c < NIT; ++c) SW += partSW[(size_t)c * BN + e];
  #pragma unroll
  for (int c = 0; c < NJT; ++c) SWT += partSWT[(size_t)c * BN + e];

  int r = refrac_in[e];
  int rd = (r > 0) ? (r - 1) : r;
  bool active = (rd == 0);
  bool s = (maskS[j] >> b) & 1u;
  bool sp = (maskSP[j] >> b) & 1u;
  float cur = mem_cur[e], pot = mem_pot[e];
  float curp = mem_cur_p[e], potp = mem_pot_p[e];

  float cur_n = active ? (inp[e] + SW + cur) : cur;
  float curp_n = active ? (SWT + curp) : curp;
  float pot_n = active ? (cur_n + pot) : pot;
  float potp_n = active ? (curp_n + potp) : potp;

  pot_n *= INV_TAU_V;
  cur_n *= INV_TAU_I;
  potp_n *= INV_TAU_V;
  curp_n *= INV_TAU_I;

  if (s) pot_n = 0.0f;
  if (sp) potp_n = 0.0f;
  int rn = s ? 2 : rd;

  pot_out[e] = pot_n;
  cur_out[e] = cur_n;
  potp_out[e] = potp_n;
  curp_out[e] = curp_n;
  refrac_out[e] = (float)rn;
}

// ---------------------------------------------------------------------------
extern "C" void kernel_launch(void* const* d_in, const int* in_sizes, int n_in,
                              void* d_out, int out_size, void* d_ws, size_t ws_size,
                              hipStream_t stream) {
  const float* inp = (const float*)d_in[0];
  const float* W = (const float*)d_in[1];
  const float* mem_pot = (const float*)d_in[2];
  const float* mem_cur = (const float*)d_in[3];
  const float* mem_pot_p = (const float*)d_in[4];
  const float* mem_cur_p = (const float*)d_in[5];
  const float* st = (const float*)d_in[6];
  const int* refrac = (const int*)d_in[7];

  float* out = (float*)d_out;
  float* S_out = out;
  float* pot_out = out + BN;
  float* W_out = out + 2 * (size_t)BN;
  float* cur_out = W_out + NN;
  float* potp_out = cur_out + BN;
  float* curp_out = potp_out + BN;
  float* refrac_out = curp_out + BN;

  // Workspace layout (16B-aligned), ~24.6 MB total
  uint32_t* maskS = (uint32_t*)d_ws;                      // 16 KB
  uint32_t* maskSP = maskS + N;                           // 16 KB
  float* max_st = (float*)(maskSP + N);                   // 16 KB
  float* rowfac = max_st + N;                             // 16 KB
  unsigned short* S_bf = (unsigned short*)(rowfac + N);   // 256 KB
  float* partSW = (float*)(S_bf + BN);                    // NIT*BN*4  = 8 MB
  float* partSWT = partSW + (size_t)NIT * BN;             // NJT*BN*4  = 16 MB

  pass_a<<<N / 256, 256, 0, stream>>>(mem_pot, mem_pot_p, st, S_out, S_bf,
                                      maskS, maskSP, max_st, rowfac);
  pass_fused<<<dim3(NJT, NIT), 512, 0, stream>>>(W, S_bf, max_st, rowfac,
                                                 W_out, partSW, partSWT);
  pass_d<<<BN / 256, 256, 0, stream>>>(inp, mem_pot, mem_cur, mem_pot_p,
                                       mem_cur_p, refrac, maskS, maskSP,
                                       partSW, partSWT, pot_out, cur_out,
                                       potp_out, curp_out, refrac_out);
}